// Round 5
// baseline (68.415 us; speedup 1.0000x reference)
//
#include <hip/hip_runtime.h>

#define NB 8
#define TAPS 5

// antireflect column fetch: j in [-4, N+3]
__device__ __forceinline__ float ldc(const float* __restrict__ row, int j, int N) {
    if ((unsigned)j < (unsigned)N) return row[j];
    const int e  = (j < 0) ? 0 : (N - 1);
    const int rr = (j < 0) ? -j : (2 * (N - 1) - j);
    return 2.f * row[e] - row[rr];
}

// antireflect row+column fetch
__device__ __forceinline__ float ldrc(const float* __restrict__ plane, int m, int j, int N) {
    if ((unsigned)m < (unsigned)N) return ldc(plane + (size_t)m * N, j, N);
    const int e  = (m < 0) ? 0 : (N - 1);
    const int rm = (m < 0) ? -m : (2 * (N - 1) - m);
    return 2.f * ldc(plane + (size_t)e * N, j, N) - ldc(plane + (size_t)rm * N, j, N);
}

__device__ __forceinline__ void fma4(float4& a, float c, const float4& v) {
    a.x += c * v.x; a.y += c * v.y; a.z += c * v.z; a.w += c * v.w;
}

// Fused one-level 2D synthesis, all-b128 LDS traffic.
// Staged window: coarse cols j0=c0-4 .. j0+SW-1 (SW=TW/2+8, 16B-aligned), rows n0-2 .. n0+THc+1.
template<int TH, int TW>
__global__ __launch_bounds__(256)
void idwt_fused(const float* __restrict__ Ass, const float* __restrict__ Asd,
                const float* __restrict__ Ads, const float* __restrict__ Add,
                const float* __restrict__ h, const float* __restrict__ g,
                float* __restrict__ out, int N) {
    constexpr int THc = TH / 2;        // coarse rows per tile
    constexpr int SW  = TW / 2 + 8;    // staged cols (mult of 4, 16B-aligned rows)
    constexpr int SW4 = SW / 4;        // float4 chunks per staged row
    constexpr int RH  = THc + 4;       // staged rows incl halo
    __shared__ float Ain[4][RH][SW];
    __shared__ float Sh[TH][SW];
    __shared__ float Dh[TH][SW];

    const int b  = blockIdx.z;
    const int r0 = blockIdx.y * TH;    // output row base
    const int w0 = blockIdx.x * TW;    // output col base
    const int n0 = r0 >> 1;            // coarse row base
    const int c0 = w0 >> 1;            // coarse col base
    const int m0 = n0 - 2;             // staged row base
    const int j0 = c0 - 4;             // staged col base (16B-aligned)
    const int tid = threadIdx.x;

    float hk[2][TAPS], gk[2][TAPS];    // hk[p][t] = h[8-2t+p] (flipped polyphase)
#pragma unroll
    for (int t = 0; t < TAPS; ++t) {
        hk[0][t] = h[8 - 2 * t]; hk[1][t] = h[9 - 2 * t];
        gk[0][t] = g[8 - 2 * t]; gk[1][t] = g[9 - 2 * t];
    }

    const size_t plane = (size_t)N * N;

    // ---- phase 0: stage 4 input planes into LDS
    const bool interior = (n0 >= 2) && (n0 + THc + 2 <= N) && (c0 >= 4) && (c0 + TW / 2 + 4 <= N);
    if (interior) {
#pragma unroll
        for (int q = 0; q < 4; ++q) {
            const float* __restrict__ p =
                ((q == 0) ? Ass : (q == 1) ? Asd : (q == 2) ? Ads : Add) + (size_t)b * plane;
            const float* __restrict__ base = p + (size_t)m0 * N + j0;
            for (int e = tid; e < RH * SW4; e += 256) {
                const int r  = e / SW4;
                const int fc = e - r * SW4;
                const float4 v = *reinterpret_cast<const float4*>(base + (size_t)r * N + 4 * fc);
                *reinterpret_cast<float4*>(&Ain[q][r][4 * fc]) = v;
            }
        }
    } else {
#pragma unroll
        for (int q = 0; q < 4; ++q) {
            const float* __restrict__ p =
                ((q == 0) ? Ass : (q == 1) ? Asd : (q == 2) ? Ads : Add) + (size_t)b * plane;
            for (int e = tid; e < RH * SW; e += 256) {
                const int r = e / SW;
                const int k = e - r * SW;
                Ain[q][r][k] = ldrc(p, m0 + r, j0 + k, N);
            }
        }
    }
    __syncthreads();

    // ---- phase 1: vertical synthesis, 4 coarse cols per item, all b128
    for (int e = tid; e < THc * SW4; e += 256) {
        const int nl = e / SW4;
        const int fc = (e - nl * SW4) * 4;
        float4 s0 = {0, 0, 0, 0}, s1 = {0, 0, 0, 0}, d0 = {0, 0, 0, 0}, d1 = {0, 0, 0, 0};
#pragma unroll
        for (int t = 0; t < TAPS; ++t) {
            const float4 va = *reinterpret_cast<const float4*>(&Ain[0][nl + t][fc]);
            const float4 vb = *reinterpret_cast<const float4*>(&Ain[1][nl + t][fc]);
            const float4 vc = *reinterpret_cast<const float4*>(&Ain[2][nl + t][fc]);
            const float4 vd = *reinterpret_cast<const float4*>(&Ain[3][nl + t][fc]);
            fma4(s0, hk[0][t], va); fma4(s0, gk[0][t], vb);
            fma4(s1, hk[1][t], va); fma4(s1, gk[1][t], vb);
            fma4(d0, hk[0][t], vc); fma4(d0, gk[0][t], vd);
            fma4(d1, hk[1][t], vc); fma4(d1, gk[1][t], vd);
        }
        *reinterpret_cast<float4*>(&Sh[2 * nl][fc])     = s0;
        *reinterpret_cast<float4*>(&Sh[2 * nl + 1][fc]) = s1;
        *reinterpret_cast<float4*>(&Dh[2 * nl][fc])     = d0;
        *reinterpret_cast<float4*>(&Dh[2 * nl + 1][fc]) = d1;
    }
    __syncthreads();

    // ---- phase 2: horizontal synthesis, 8 output cols per thread, b128 reads
    const int M = 2 * N;
    constexpr int KW = TW / 8;         // 8-col chunks per row
    for (int e = tid; e < TH * KW; e += 256) {
        const int r = e / KW;
        const int u = e - r * KW;
        float sv[12], dv[12];
        *reinterpret_cast<float4*>(&sv[0]) = *reinterpret_cast<const float4*>(&Sh[r][4 * u]);
        *reinterpret_cast<float4*>(&sv[4]) = *reinterpret_cast<const float4*>(&Sh[r][4 * u + 4]);
        *reinterpret_cast<float4*>(&sv[8]) = *reinterpret_cast<const float4*>(&Sh[r][4 * u + 8]);
        *reinterpret_cast<float4*>(&dv[0]) = *reinterpret_cast<const float4*>(&Dh[r][4 * u]);
        *reinterpret_cast<float4*>(&dv[4]) = *reinterpret_cast<const float4*>(&Dh[r][4 * u + 4]);
        *reinterpret_cast<float4*>(&dv[8]) = *reinterpret_cast<const float4*>(&Dh[r][4 * u + 8]);
        float o[8];
#pragma unroll
        for (int cc = 0; cc < 4; ++cc) {
            float o0 = 0.f, o1 = 0.f;
#pragma unroll
            for (int t = 0; t < TAPS; ++t) {
                const float sx = sv[cc + t + 2], dx = dv[cc + t + 2];
                o0 += hk[0][t] * sx + gk[0][t] * dx;
                o1 += hk[1][t] * sx + gk[1][t] * dx;
            }
            o[2 * cc] = o0; o[2 * cc + 1] = o1;
        }
        float* dst = out + ((size_t)b * M + (r0 + r)) * M + w0 + 8 * u;
        *reinterpret_cast<float4*>(dst)     = make_float4(o[0], o[1], o[2], o[3]);
        *reinterpret_cast<float4*>(dst + 4) = make_float4(o[4], o[5], o[6], o[7]);
    }
}

extern "C" void kernel_launch(void* const* d_in, const int* in_sizes, int n_in,
                              void* d_out, int out_size, void* d_ws, size_t ws_size,
                              hipStream_t stream) {
    const float* ss = (const float*)d_in[0];
    const float* sd[3] = {(const float*)d_in[1], (const float*)d_in[2], (const float*)d_in[3]};
    const float* ds[3] = {(const float*)d_in[4], (const float*)d_in[5], (const float*)d_in[6]};
    const float* dd[3] = {(const float*)d_in[7], (const float*)d_in[8], (const float*)d_in[9]};
    const float* h = (const float*)d_in[10];
    const float* g = (const float*)d_in[11];
    float* out = (float*)d_out;

    // ws: I0 = level-2 output (2 MiB), I1 = level-1 output (8 MiB). Distinct
    // buffers: the fused kernel reads its input while writing its output.
    char* ws = (char*)d_ws;
    float* I0 = (float*)ws;
    float* I1 = (float*)(ws + ((size_t)2 << 20));

    // level 2: 128 -> 256
    {
        const int N = 128, M = 256;
        constexpr int TH = 16, TW = 32;
        dim3 grid(M / TW, M / TH, NB);
        idwt_fused<TH, TW><<<grid, 256, 0, stream>>>(ss, sd[2], ds[2], dd[2], h, g, I0, N);
    }
    // level 1: 256 -> 512
    {
        const int N = 256, M = 512;
        constexpr int TH = 32, TW = 64;
        dim3 grid(M / TW, M / TH, NB);
        idwt_fused<TH, TW><<<grid, 256, 0, stream>>>(I0, sd[1], ds[1], dd[1], h, g, I1, N);
    }
    // level 0: 512 -> 1024
    {
        const int N = 512, M = 1024;
        constexpr int TH = 32, TW = 64;
        dim3 grid(M / TW, M / TH, NB);
        idwt_fused<TH, TW><<<grid, 256, 0, stream>>>(I1, sd[0], ds[0], dd[0], h, g, out, N);
    }
}